// Round 3
// baseline (301.876 us; speedup 1.0000x reference)
//
#include <hip/hip_runtime.h>
#include <hip/hip_bf16.h>
#include <math.h>

#define B_ 1024
#define S_ 200
#define D_ 128
#define H_ 128
#define N_ 64

typedef __attribute__((ext_vector_type(8))) short short8;
typedef __attribute__((ext_vector_type(8))) __bf16 bf16x8;
typedef __attribute__((ext_vector_type(4))) float floatx4;

static __device__ __forceinline__ float bf2f(unsigned short u) {
    union { unsigned int i; float f; } v; v.i = ((unsigned int)u) << 16; return v.f;
}
static __device__ __forceinline__ unsigned short f2bf(float f) {
    union { float f; unsigned int u; } v; v.f = f;
    unsigned int u = v.u;
    return (unsigned short)((u + 0x7FFFu + ((u >> 16) & 1u)) >> 16);   // RNE
}
static __device__ __forceinline__ float ld1(const void* p, int isbf, size_t i) {
    return isbf ? bf2f(((const unsigned short*)p)[i]) : ((const float*)p)[i];
}

// ---------------- K-1: dtype detection ----------------
// For each float input, sample low half-words of u32 words. Real bf16 data has
// bf16-exponent field in [96,140] (or 0) ~100% of the time; f32 data's low halves
// are mantissa bits -> ~18% pass. flags[i]=1 means bf16. flags[3]=1: byte mask.
__global__ __launch_bounds__(64) void detect_kernel(
    const void* a0, const void* a1, const void* a2, const void* a3,
    const void* a4, const void* a5, const void* a6, const void* a7,
    int* flags)
{
    int bid = blockIdx.x, t = threadIdx.x;
    if (bid == 3) {
        const unsigned char* mb = (const unsigned char*)a3;
        int f = 0;
        for (int i = t; i < 4096; i += 64)
            if ((i & 3) && mb[i]) f = 1;
        for (int off = 32; off; off >>= 1) f |= __shfl_xor(f, off, 64);
        if (t == 0) flags[3] = f;          // 1 => uint8 mask, 0 => int32 mask
        return;
    }
    const void* ptrs[8] = {a0, a1, a2, a3, a4, a5, a6, a7};
    const int counts[8] = {B_*S_*D_, S_*D_, B_*D_, 0, B_*N_*D_, D_*H_, D_*H_, H_};
    const unsigned int* w = (const unsigned int*)ptrs[bid];
    int words = counts[bid] / 2; if (words > 1024) words = 1024;  // safe under bf16 interp
    int pass = 0, tot = 0;
    for (int i = t; i < words; i += 64) {
        unsigned int e = (w[i] >> 7) & 0xFF;
        tot++;
        if (e == 0 || (e >= 96 && e <= 140)) pass++;
    }
    for (int off = 32; off; off >>= 1) {
        pass += __shfl_xor(pass, off, 64);
        tot  += __shfl_xor(tot,  off, 64);
    }
    if (t == 0) flags[bid] = (pass * 4 >= tot * 3) ? 1 : 0;
}

// ---------------- K0: pb[s][h] = sum_d pos[s][d] * Wp[d][h] ----------------
__global__ __launch_bounds__(128) void pb_kernel(
    const void* __restrict__ pos, const void* __restrict__ Wp,
    const int* __restrict__ flags, float* __restrict__ pb)
{
    int s = blockIdx.x, h = threadIdx.x;
    int fpos = flags[1], fWp = flags[5];
    __shared__ float prow[D_];
    prow[h] = ld1(pos, fpos, (size_t)s * D_ + h);
    __syncthreads();
    float acc = 0.f;
    if (fWp) {
        const unsigned short* W = (const unsigned short*)Wp;
        for (int d = 0; d < D_; ++d) acc = fmaf(prow[d], bf2f(W[d * H_ + h]), acc);
    } else {
        const float* W = (const float*)Wp;
        for (int d = 0; d < D_; ++d) acc = fmaf(prow[d], W[d * H_ + h], acc);
    }
    pb[s * H_ + h] = acc;
}

// ---------------- K1: scores[row] = sum_h z[h]*tanh((X@We)[row,h] + pb[row%S,h]) ----------------
__global__ __launch_bounds__(256) void scores_kernel(
    const void* __restrict__ Xs, const void* __restrict__ We,
    const void* __restrict__ zv, const float* __restrict__ pb,
    const int* __restrict__ flags, float* __restrict__ scores)
{
    __shared__ unsigned short As[64][136];
    __shared__ unsigned short Bs[128][136];
    __shared__ float zsh[H_];

    int t = threadIdx.x;
    int row0 = blockIdx.x * 64;
    int fXs = flags[0], fWe = flags[6], fz = flags[7];

    // stage We transposed: Bs[h][d]
    for (int c = t; c < 2048; c += 256) {
        int d = c >> 4, h8 = (c & 15) * 8;
        unsigned short tmp[8];
        if (fWe) {
            short8 v = *(const short8*)((const unsigned short*)We + d * H_ + h8);
#pragma unroll
            for (int j = 0; j < 8; ++j) tmp[j] = (unsigned short)v[j];
        } else {
            const float* Wf = (const float*)We + d * H_ + h8;
            float4 v0 = *(const float4*)Wf;
            float4 v1 = *(const float4*)(Wf + 4);
            tmp[0] = f2bf(v0.x); tmp[1] = f2bf(v0.y); tmp[2] = f2bf(v0.z); tmp[3] = f2bf(v0.w);
            tmp[4] = f2bf(v1.x); tmp[5] = f2bf(v1.y); tmp[6] = f2bf(v1.z); tmp[7] = f2bf(v1.w);
        }
#pragma unroll
        for (int j = 0; j < 8; ++j) Bs[h8 + j][d] = tmp[j];
    }
    // stage A rows (contiguous k)
    for (int c = t; c < 1024; c += 256) {
        int r = c >> 4, c8 = (c & 15) * 8;
        short8 v;
        if (fXs) {
            v = *(const short8*)((const unsigned short*)Xs + (size_t)(row0 + r) * D_ + c8);
        } else {
            const float* Xf = (const float*)Xs + (size_t)(row0 + r) * D_ + c8;
            float4 v0 = *(const float4*)Xf;
            float4 v1 = *(const float4*)(Xf + 4);
            v[0] = (short)f2bf(v0.x); v[1] = (short)f2bf(v0.y);
            v[2] = (short)f2bf(v0.z); v[3] = (short)f2bf(v0.w);
            v[4] = (short)f2bf(v1.x); v[5] = (short)f2bf(v1.y);
            v[6] = (short)f2bf(v1.z); v[7] = (short)f2bf(v1.w);
        }
        *(short8*)(&As[r][c8]) = v;
    }
    if (t < H_) zsh[t] = ld1(zv, fz, t);
    __syncthreads();

    int lane = t & 63, w = t >> 6;
    int quad = lane >> 4, mrow = lane & 15;
    int mbase = w * 16;

    floatx4 acc[8];
#pragma unroll
    for (int i = 0; i < 8; ++i) { acc[i][0] = 0.f; acc[i][1] = 0.f; acc[i][2] = 0.f; acc[i][3] = 0.f; }

#pragma unroll
    for (int kk = 0; kk < 128; kk += 32) {
        short8 a = *(const short8*)(&As[mbase + mrow][kk + quad * 8]);
        bf16x8 af = __builtin_bit_cast(bf16x8, a);
#pragma unroll
        for (int nt = 0; nt < 8; ++nt) {
            short8 b = *(const short8*)(&Bs[nt * 16 + mrow][kk + quad * 8]);
            bf16x8 bf = __builtin_bit_cast(bf16x8, b);
            acc[nt] = __builtin_amdgcn_mfma_f32_16x16x32_bf16(af, bf, acc[nt], 0, 0, 0);
        }
    }

    // epilogue: C layout col=lane&15, row=quad*4+reg
    int col = mrow;
    float rowsum[4];
#pragma unroll
    for (int reg = 0; reg < 4; ++reg) {
        int grow = row0 + mbase + quad * 4 + reg;
        int s = grow % S_;
        const float* pbrow = pb + (size_t)s * H_;
        float rs = 0.f;
#pragma unroll
        for (int nt = 0; nt < 8; ++nt) {
            int h = nt * 16 + col;
            float v = tanhf(acc[nt][reg] + pbrow[h]);
            rs = fmaf(v, zsh[h], rs);
        }
        rowsum[reg] = rs;
    }
#pragma unroll
    for (int off = 1; off < 16; off <<= 1) {
#pragma unroll
        for (int reg = 0; reg < 4; ++reg)
            rowsum[reg] += __shfl_xor(rowsum[reg], off, 64);
    }
    if (mrow == 0) {
#pragma unroll
        for (int reg = 0; reg < 4; ++reg)
            scores[row0 + mbase + quad * 4 + reg] = rowsum[reg];
    }
}

// ---------------- K2: per-b softmax, weighted sum, inner, pos/neg losses ----------------
__global__ __launch_bounds__(256) void perB_kernel(
    const void* __restrict__ Xs, const void* __restrict__ Xitem,
    const void* __restrict__ maskv, const void* __restrict__ origin,
    const float* __restrict__ scores, const int* __restrict__ flags,
    float* __restrict__ pos_loss, float* __restrict__ neg_sum,
    float* __restrict__ out)                   // concated [B,(D+1)] f32
{
    int b = blockIdx.x, t = threadIdx.x;
    int fXs = flags[0], fXi = flags[2], fMk = flags[3], fOr = flags[4];
    __shared__ float attn[S_];
    __shared__ float att_out[D_];
    __shared__ float lastv[D_];
    __shared__ float outv[D_];
    __shared__ float partial[8][D_];
    __shared__ float red[16];
    __shared__ int icnt;
    __shared__ float sc1, sc2, sc3;

    if (t == 0) icnt = 0;
    __syncthreads();

    if (t < S_) {
        int nz = fMk ? (((const unsigned char*)maskv)[(size_t)b * S_ + t] != 0)
                     : (((const int*)maskv)[(size_t)b * S_ + t] != 0);
        if (nz) atomicAdd(&icnt, 1);
    }
    __syncthreads();
    int length = icnt;           // valid prefix length, >= 1
    int last = length - 1;

    // --- softmax over valid prefix ---
    float sc = (t < length) ? scores[(size_t)b * S_ + t] : -INFINITY;
    float m = sc;
    for (int off = 32; off; off >>= 1) m = fmaxf(m, __shfl_xor(m, off, 64));
    if ((t & 63) == 0) red[t >> 6] = m;
    __syncthreads();
    if (t == 0) sc1 = fmaxf(fmaxf(red[0], red[1]), fmaxf(red[2], red[3]));
    __syncthreads();
    float e = (t < length) ? expf(sc - sc1) : 0.f;
    float r = e;
    for (int off = 32; off; off >>= 1) r += __shfl_xor(r, off, 64);
    __syncthreads();
    if ((t & 63) == 0) red[t >> 6] = r;
    __syncthreads();
    if (t == 0) sc2 = red[0] + red[1] + red[2] + red[3];
    __syncthreads();
    if (t < S_) attn[t] = e / sc2;
    __syncthreads();

    // --- attention_output[d] = sum_s attn[s] * X[b,s,d] ---
    {
        int part = t >> 5;             // 0..7
        int d4 = (t & 31) * 4;
        float a0 = 0, a1 = 0, a2 = 0, a3 = 0;
        if (fXs) {
            for (int s = part; s < length; s += 8) {
                float ww = attn[s];
                uint2 u = *(const uint2*)((const unsigned short*)Xs + ((size_t)b * S_ + s) * D_ + d4);
                a0 = fmaf(ww, bf2f((unsigned short)(u.x & 0xffff)), a0);
                a1 = fmaf(ww, bf2f((unsigned short)(u.x >> 16)), a1);
                a2 = fmaf(ww, bf2f((unsigned short)(u.y & 0xffff)), a2);
                a3 = fmaf(ww, bf2f((unsigned short)(u.y >> 16)), a3);
            }
        } else {
            for (int s = part; s < length; s += 8) {
                float ww = attn[s];
                float4 u = *(const float4*)((const float*)Xs + ((size_t)b * S_ + s) * D_ + d4);
                a0 = fmaf(ww, u.x, a0);
                a1 = fmaf(ww, u.y, a1);
                a2 = fmaf(ww, u.z, a2);
                a3 = fmaf(ww, u.w, a3);
            }
        }
        partial[part][d4] = a0; partial[part][d4 + 1] = a1;
        partial[part][d4 + 2] = a2; partial[part][d4 + 3] = a3;
    }
    __syncthreads();
    if (t < D_) {
        float v = 0.f;
#pragma unroll
        for (int p = 0; p < 8; ++p) v += partial[p][t];
        att_out[t] = v;
        float lv = attn[last] * ld1(Xs, fXs, ((size_t)b * S_ + last) * D_ + t);
        lastv[t] = lv;
        outv[t] = v - lv;       // out_vec = attention_output - last_vec
    }
    __syncthreads();

    // --- inner = dot(att_out, X_item[b]); write concated row (f32) ---
    {
        float pi = (t < D_) ? att_out[t] * ld1(Xitem, fXi, (size_t)b * D_ + t) : 0.f;
        for (int off = 32; off; off >>= 1) pi += __shfl_xor(pi, off, 64);
        if ((t & 63) == 0) red[t >> 6] = pi;
        __syncthreads();
        if (t < D_) out[(size_t)b * (D_ + 1) + t] = att_out[t];
        if (t == 0)
            out[(size_t)b * (D_ + 1) + D_] = red[0] + red[1] + red[2] + red[3];
        __syncthreads();   // protect red[] before pos-loss section reuses it
    }

    // --- pos loss: cos(last_vec, out_vec) ---
    {
        float l_ = (t < D_) ? lastv[t] : 0.f;
        float o_ = (t < D_) ? outv[t] : 0.f;
        float r0 = l_ * l_, r1 = l_ * o_, r2 = o_ * o_;
        for (int off = 32; off; off >>= 1) {
            r0 += __shfl_xor(r0, off, 64);
            r1 += __shfl_xor(r1, off, 64);
            r2 += __shfl_xor(r2, off, 64);
        }
        if ((t & 63) == 0) { int wi = t >> 6; red[wi] = r0; red[4 + wi] = r1; red[8 + wi] = r2; }
        __syncthreads();
        if (t == 0) {
            float ll = red[0] + red[1] + red[2] + red[3];
            float lo = red[4] + red[5] + red[6] + red[7];
            float oo = red[8] + red[9] + red[10] + red[11];
            float cosv = lo / (sqrtf(fmaxf(ll, 1e-12f)) * sqrtf(fmaxf(oo, 1e-12f)));
            float pl = 0.5f * (1.f - cosv);
            pos_loss[b] = log1pf(expf(-pl));
            sc3 = oo;
        }
        __syncthreads();
    }

    // --- neg losses: 64 origin vectors, 16 per wave ---
    {
        int w = t >> 6, lane = t & 63;
        int d = lane * 2;
        float v0 = outv[d], v1 = outv[d + 1];
        float vv = sc3;
        float accs = 0.f;
        for (int n = w; n < N_; n += 4) {
            size_t base = ((size_t)b * N_ + n) * D_ + d;
            float o0, o1;
            if (fOr) {
                unsigned int u = *(const unsigned int*)((const unsigned short*)origin + base);
                o0 = bf2f((unsigned short)(u & 0xffff));
                o1 = bf2f((unsigned short)(u >> 16));
            } else {
                float2 u = *(const float2*)((const float*)origin + base);
                o0 = u.x; o1 = u.y;
            }
            float oo = o0 * o0 + o1 * o1;
            float ov = o0 * v0 + o1 * v1;
            for (int off = 32; off; off >>= 1) {
                oo += __shfl_xor(oo, off, 64);
                ov += __shfl_xor(ov, off, 64);
            }
            float cosn = ov / (sqrtf(fmaxf(oo, 1e-12f)) * sqrtf(fmaxf(vv, 1e-12f)));
            float nl = 0.5f * (1.f - cosn);
            accs += log1pf(expf(nl));
        }
        __syncthreads();
        if (lane == 0) red[w] = accs;
        __syncthreads();
        if (t == 0) neg_sum[b] = red[0] + red[1] + red[2] + red[3];
    }
}

// ---------------- K3: aux[b] = sum_b'(pos_loss) + neg_sum[b] (f32) ----------------
__global__ __launch_bounds__(1024) void final_kernel(
    const float* __restrict__ pos_loss,
    const float* __restrict__ neg_sum,
    float* __restrict__ out)
{
    __shared__ float red[16];
    int t = threadIdx.x;
    float v = pos_loss[t];
    for (int off = 32; off; off >>= 1) v += __shfl_xor(v, off, 64);
    if ((t & 63) == 0) red[t >> 6] = v;
    __syncthreads();
    if (t == 0) {
        float s = 0.f;
#pragma unroll
        for (int i = 0; i < 16; ++i) s += red[i];
        red[0] = s;
    }
    __syncthreads();
    out[(size_t)B_ * (D_ + 1) + t] = red[0] + neg_sum[t];
}

extern "C" void kernel_launch(void* const* d_in, const int* in_sizes, int n_in,
                              void* d_out, int out_size, void* d_ws, size_t ws_size,
                              hipStream_t stream) {
    const void* Xs     = d_in[0]; // X_series [B,S,D]
    const void* pos    = d_in[1]; // pos_series [S,D]
    const void* Xitem  = d_in[2]; // X_item [B,D]
    const void* mask   = d_in[3]; // valid_mask [B,S]
    const void* origin = d_in[4]; // origin [B,N,D]
    const void* Wp     = d_in[5]; // [D,H]
    const void* We     = d_in[6]; // [D,H]
    const void* zv     = d_in[7]; // [H]

    int*   flags    = (int*)d_ws;                   // 32 ints
    float* ws       = (float*)d_ws;
    float* pb       = ws + 32;                      // 25600 f32
    float* scores   = pb + 25600;                   // 204800 f32
    float* pos_loss = scores + 204800;              // 1024 f32
    float* neg_sum  = pos_loss + B_;                // 1024 f32
    float* out = (float*)d_out;                     // f32 output (reference dtype)

    detect_kernel<<<8, 64, 0, stream>>>(Xs, pos, Xitem, mask, origin, Wp, We, zv, flags);
    pb_kernel<<<S_, 128, 0, stream>>>(pos, Wp, flags, pb);
    scores_kernel<<<(B_ * S_) / 64, 256, 0, stream>>>(Xs, We, zv, pb, flags, scores);
    perB_kernel<<<B_, 256, 0, stream>>>(Xs, Xitem, mask, origin, scores, flags, pos_loss, neg_sum, out);
    final_kernel<<<1, 1024, 0, stream>>>(pos_loss, neg_sum, out);
}

// Round 4
// 286.958 us; speedup vs baseline: 1.0520x; 1.0520x over previous
//
#include <hip/hip_runtime.h>
#include <hip/hip_bf16.h>
#include <math.h>

#define B_ 1024
#define S_ 200
#define D_ 128
#define H_ 128
#define N_ 64

typedef __attribute__((ext_vector_type(8))) short short8;
typedef __attribute__((ext_vector_type(8))) __bf16 bf16x8;
typedef __attribute__((ext_vector_type(4))) float floatx4;

static __device__ __forceinline__ float bf2f(unsigned short u) {
    union { unsigned int i; float f; } v; v.i = ((unsigned int)u) << 16; return v.f;
}
static __device__ __forceinline__ unsigned short f2bf(float f) {
    union { float f; unsigned int u; } v; v.f = f;
    unsigned int u = v.u;
    return (unsigned short)((u + 0x7FFFu + ((u >> 16) & 1u)) >> 16);   // RNE
}
static __device__ __forceinline__ float ld1(const void* p, int isbf, size_t i) {
    return isbf ? bf2f(((const unsigned short*)p)[i]) : ((const float*)p)[i];
}
static __device__ __forceinline__ float fast_tanh(float x) {
    float t = __expf(2.0f * x);
    return 1.0f - 2.0f * __builtin_amdgcn_rcpf(t + 1.0f);   // exact at +/-inf, err ~2e-5
}

// ---------------- K-1: dtype detection ----------------
__global__ __launch_bounds__(64) void detect_kernel(
    const void* a0, const void* a1, const void* a2, const void* a3,
    const void* a4, const void* a5, const void* a6, const void* a7,
    int* flags)
{
    int bid = blockIdx.x, t = threadIdx.x;
    if (bid == 3) {
        const unsigned char* mb = (const unsigned char*)a3;
        int f = 0;
        for (int i = t; i < 4096; i += 64)
            if ((i & 3) && mb[i]) f = 1;
        for (int off = 32; off; off >>= 1) f |= __shfl_xor(f, off, 64);
        if (t == 0) flags[3] = f;          // 1 => uint8 mask, 0 => int32 mask
        return;
    }
    const void* ptrs[8] = {a0, a1, a2, a3, a4, a5, a6, a7};
    const int counts[8] = {B_*S_*D_, S_*D_, B_*D_, 0, B_*N_*D_, D_*H_, D_*H_, H_};
    const unsigned int* w = (const unsigned int*)ptrs[bid];
    int words = counts[bid] / 2; if (words > 1024) words = 1024;
    int pass = 0, tot = 0;
    for (int i = t; i < words; i += 64) {
        unsigned int e = (w[i] >> 7) & 0xFF;
        tot++;
        if (e == 0 || (e >= 96 && e <= 140)) pass++;
    }
    for (int off = 32; off; off >>= 1) {
        pass += __shfl_xor(pass, off, 64);
        tot  += __shfl_xor(tot,  off, 64);
    }
    if (t == 0) flags[bid] = (pass * 4 >= tot * 3) ? 1 : 0;
}

// ---------------- prep: WeT[h][d] = bf16(We[d][h]) (one-off 32 KB transpose) ----------------
__global__ __launch_bounds__(1024) void prep_kernel(
    const void* __restrict__ We, const int* __restrict__ flags,
    unsigned short* __restrict__ WeT)
{
    __shared__ unsigned short T[128][136];   // +8 pad, rows 16B-aligned (272 B)
    int t = threadIdx.x;
    int fWe = flags[6];
    for (int c = t; c < 2048; c += 1024) {
        int d = c >> 4, h8 = (c & 15) * 8;
        short8 v;
        if (fWe) {
            v = *(const short8*)((const unsigned short*)We + d * H_ + h8);
        } else {
            const float* p = (const float*)We + d * H_ + h8;
            float4 a = ((const float4*)p)[0], b = ((const float4*)p)[1];
            v[0] = (short)f2bf(a.x); v[1] = (short)f2bf(a.y);
            v[2] = (short)f2bf(a.z); v[3] = (short)f2bf(a.w);
            v[4] = (short)f2bf(b.x); v[5] = (short)f2bf(b.y);
            v[6] = (short)f2bf(b.z); v[7] = (short)f2bf(b.w);
        }
        *(short8*)(&T[d][h8]) = v;
    }
    __syncthreads();
    for (int c = t; c < 2048; c += 1024) {
        int h = c >> 4, d8 = (c & 15) * 8;
        short8 v;
#pragma unroll
        for (int j = 0; j < 8; ++j) v[j] = (short)T[d8 + j][h];
        *(short8*)(WeT + h * D_ + d8) = v;
    }
}

// ---------------- K0: pb[s][h] = sum_d pos[s][d] * Wp[d][h] ----------------
__global__ __launch_bounds__(128) void pb_kernel(
    const void* __restrict__ pos, const void* __restrict__ Wp,
    const int* __restrict__ flags, float* __restrict__ pb)
{
    int s = blockIdx.x, h = threadIdx.x;
    int fpos = flags[1], fWp = flags[5];
    __shared__ float prow[D_];
    prow[h] = ld1(pos, fpos, (size_t)s * D_ + h);
    __syncthreads();
    float acc = 0.f;
    if (fWp) {
        const unsigned short* W = (const unsigned short*)Wp;
        for (int d = 0; d < D_; ++d) acc = fmaf(prow[d], bf2f(W[d * H_ + h]), acc);
    } else {
        const float* W = (const float*)Wp;
        for (int d = 0; d < D_; ++d) acc = fmaf(prow[d], W[d * H_ + h], acc);
    }
    pb[s * H_ + h] = acc;
}

// ---------------- K1: scores — LDS-free MFMA GEMM + fused tanh epilogue ----------------
// Block = 256 thr (4 waves), M=128 rows/block (32/wave = 2 m-tiles), N=128, K=128.
// A fragments: X rows, f32->bf16 in regs. B fragments: WeT rows (L1/L2-hot).
__global__ __launch_bounds__(256) void scores_kernel(
    const void* __restrict__ Xs, const unsigned short* __restrict__ WeT,
    const void* __restrict__ zv, const float* __restrict__ pb,
    const int* __restrict__ flags, float* __restrict__ scores)
{
    int t = threadIdx.x;
    int lane = t & 63, w = t >> 6;
    int quad = lane >> 4, mrow = lane & 15;
    int fXs = flags[0], fz = flags[7];
    int row0 = blockIdx.x * 128 + w * 32;   // this wave's first row

    float zl[8];
#pragma unroll
    for (int nt = 0; nt < 8; ++nt) zl[nt] = ld1(zv, fz, nt * 16 + mrow);

    floatx4 acc[2][8];
#pragma unroll
    for (int mt = 0; mt < 2; ++mt)
#pragma unroll
        for (int nt = 0; nt < 8; ++nt) {
            acc[mt][nt][0] = 0.f; acc[mt][nt][1] = 0.f;
            acc[mt][nt][2] = 0.f; acc[mt][nt][3] = 0.f;
        }

#pragma unroll
    for (int kk = 0; kk < 128; kk += 32) {
        bf16x8 af[2];
#pragma unroll
        for (int mt = 0; mt < 2; ++mt) {
            size_t roff = (size_t)(row0 + mt * 16 + mrow) * D_ + kk + quad * 8;
            if (fXs) {
                short8 v = *(const short8*)((const unsigned short*)Xs + roff);
                af[mt] = __builtin_bit_cast(bf16x8, v);
            } else {
                const float* p = (const float*)Xs + roff;
                float4 a = ((const float4*)p)[0], b = ((const float4*)p)[1];
                short8 v;
                v[0] = (short)f2bf(a.x); v[1] = (short)f2bf(a.y);
                v[2] = (short)f2bf(a.z); v[3] = (short)f2bf(a.w);
                v[4] = (short)f2bf(b.x); v[5] = (short)f2bf(b.y);
                v[6] = (short)f2bf(b.z); v[7] = (short)f2bf(b.w);
                af[mt] = __builtin_bit_cast(bf16x8, v);
            }
        }
#pragma unroll
        for (int nt = 0; nt < 8; ++nt) {
            short8 bv = *(const short8*)(WeT + (nt * 16 + mrow) * D_ + kk + quad * 8);
            bf16x8 bf = __builtin_bit_cast(bf16x8, bv);
            acc[0][nt] = __builtin_amdgcn_mfma_f32_16x16x32_bf16(af[0], bf, acc[0][nt], 0, 0, 0);
            acc[1][nt] = __builtin_amdgcn_mfma_f32_16x16x32_bf16(af[1], bf, acc[1][nt], 0, 0, 0);
        }
    }

    // epilogue: C layout col=lane&15 (=mrow), row=quad*4+reg
#pragma unroll
    for (int mt = 0; mt < 2; ++mt) {
#pragma unroll
        for (int reg = 0; reg < 4; ++reg) {
            int grow = row0 + mt * 16 + quad * 4 + reg;
            int s = grow % S_;
            const float* pbrow = pb + (size_t)s * H_;
            float rs = 0.f;
#pragma unroll
            for (int nt = 0; nt < 8; ++nt) {
                float v = fast_tanh(acc[mt][nt][reg] + pbrow[nt * 16 + mrow]);
                rs = fmaf(v, zl[nt], rs);
            }
#pragma unroll
            for (int off = 1; off < 16; off <<= 1)
                rs += __shfl_xor(rs, off, 64);
            if (mrow == 0) scores[grow] = rs;
        }
    }
}

// ---------------- K2: per-b softmax, weighted sum, inner, pos/neg losses ----------------
__global__ __launch_bounds__(256) void perB_kernel(
    const void* __restrict__ Xs, const void* __restrict__ Xitem,
    const void* __restrict__ maskv, const void* __restrict__ origin,
    const float* __restrict__ scores, const int* __restrict__ flags,
    float* __restrict__ pos_loss, float* __restrict__ neg_sum,
    float* __restrict__ out)                   // concated [B,(D+1)] f32
{
    int b = blockIdx.x, t = threadIdx.x;
    int wv = t >> 6, lane = t & 63;
    int fXs = flags[0], fXi = flags[2], fMk = flags[3], fOr = flags[4];
    __shared__ float attn[256];         // attn[s]=0 for s>=length (incl. padding)
    __shared__ float att_out[D_];
    __shared__ float lastv[D_];
    __shared__ float outv[D_];
    __shared__ float partial[8][D_];
    __shared__ float red[16];
    __shared__ int redi[4];
    __shared__ float sc1, sc2, sc3;

    // --- length via ballot (mask is a contiguous prefix) ---
    int nz = 0;
    if (t < S_)
        nz = fMk ? (((const unsigned char*)maskv)[(size_t)b * S_ + t] != 0)
                 : (((const int*)maskv)[(size_t)b * S_ + t] != 0);
    unsigned long long bal = __ballot(nz);
    if (lane == 0) redi[wv] = __popcll(bal);
    __syncthreads();
    int length = redi[0] + redi[1] + redi[2] + redi[3];   // >= 1
    int last = length - 1;

    // --- softmax over valid prefix ---
    float sc = (t < length) ? scores[(size_t)b * S_ + t] : -INFINITY;
    float m = sc;
    for (int off = 32; off; off >>= 1) m = fmaxf(m, __shfl_xor(m, off, 64));
    if (lane == 0) red[wv] = m;
    __syncthreads();
    if (t == 0) sc1 = fmaxf(fmaxf(red[0], red[1]), fmaxf(red[2], red[3]));
    __syncthreads();
    float e = (t < length) ? expf(sc - sc1) : 0.f;
    float r = e;
    for (int off = 32; off; off >>= 1) r += __shfl_xor(r, off, 64);
    __syncthreads();
    if (lane == 0) red[wv] = r;
    __syncthreads();
    if (t == 0) sc2 = red[0] + red[1] + red[2] + red[3];
    __syncthreads();
    attn[t] = e / sc2;       // zero beyond length; attn[200..255] zero too
    __syncthreads();

    // --- attention_output[d] = sum_s attn[s] * X[b,s,d]; fixed 25-trip loop ---
    {
        int part = t >> 5;             // 0..7 (s offset)
        int d4 = (t & 31) * 4;         // 4 contiguous d
        float a0 = 0, a1 = 0, a2 = 0, a3 = 0;
        if (fXs) {
#pragma unroll 5
            for (int s = part; s < S_; s += 8) {
                float ww = attn[s];
                uint2 u = *(const uint2*)((const unsigned short*)Xs + ((size_t)b * S_ + s) * D_ + d4);
                a0 = fmaf(ww, bf2f((unsigned short)(u.x & 0xffff)), a0);
                a1 = fmaf(ww, bf2f((unsigned short)(u.x >> 16)), a1);
                a2 = fmaf(ww, bf2f((unsigned short)(u.y & 0xffff)), a2);
                a3 = fmaf(ww, bf2f((unsigned short)(u.y >> 16)), a3);
            }
        } else {
#pragma unroll 5
            for (int s = part; s < S_; s += 8) {
                float ww = attn[s];
                float4 u = *(const float4*)((const float*)Xs + ((size_t)b * S_ + s) * D_ + d4);
                a0 = fmaf(ww, u.x, a0);
                a1 = fmaf(ww, u.y, a1);
                a2 = fmaf(ww, u.z, a2);
                a3 = fmaf(ww, u.w, a3);
            }
        }
        partial[part][d4] = a0; partial[part][d4 + 1] = a1;
        partial[part][d4 + 2] = a2; partial[part][d4 + 3] = a3;
    }
    __syncthreads();
    if (t < D_) {
        float v = 0.f;
#pragma unroll
        for (int p = 0; p < 8; ++p) v += partial[p][t];
        att_out[t] = v;
        float lv = attn[last] * ld1(Xs, fXs, ((size_t)b * S_ + last) * D_ + t);
        lastv[t] = lv;
        outv[t] = v - lv;       // out_vec = attention_output - last_vec
    }
    __syncthreads();

    // --- inner = dot(att_out, X_item[b]); write concated row (f32) ---
    {
        float pi = (t < D_) ? att_out[t] * ld1(Xitem, fXi, (size_t)b * D_ + t) : 0.f;
        for (int off = 32; off; off >>= 1) pi += __shfl_xor(pi, off, 64);
        if (lane == 0) red[wv] = pi;
        __syncthreads();
        if (t < D_) out[(size_t)b * (D_ + 1) + t] = att_out[t];
        if (t == 0)
            out[(size_t)b * (D_ + 1) + D_] = red[0] + red[1] + red[2] + red[3];
        __syncthreads();
    }

    // --- pos loss: cos(last_vec, out_vec) ---
    {
        float l_ = (t < D_) ? lastv[t] : 0.f;
        float o_ = (t < D_) ? outv[t] : 0.f;
        float r0 = l_ * l_, r1 = l_ * o_, r2 = o_ * o_;
        for (int off = 32; off; off >>= 1) {
            r0 += __shfl_xor(r0, off, 64);
            r1 += __shfl_xor(r1, off, 64);
            r2 += __shfl_xor(r2, off, 64);
        }
        if (lane == 0) { red[wv] = r0; red[4 + wv] = r1; red[8 + wv] = r2; }
        __syncthreads();
        if (t == 0) {
            float ll = red[0] + red[1] + red[2] + red[3];
            float lo = red[4] + red[5] + red[6] + red[7];
            float oo = red[8] + red[9] + red[10] + red[11];
            float cosv = lo / (sqrtf(fmaxf(ll, 1e-12f)) * sqrtf(fmaxf(oo, 1e-12f)));
            float pl = 0.5f * (1.f - cosv);
            pos_loss[b] = log1pf(expf(-pl));
            sc3 = oo;
        }
        __syncthreads();
    }

    // --- neg losses: 64 origin vectors, 16 per wave ---
    {
        int d = lane * 2;
        float v0 = outv[d], v1 = outv[d + 1];
        float vv = sc3;
        float accs = 0.f;
        for (int n = wv; n < N_; n += 4) {
            size_t base = ((size_t)b * N_ + n) * D_ + d;
            float o0, o1;
            if (fOr) {
                unsigned int u = *(const unsigned int*)((const unsigned short*)origin + base);
                o0 = bf2f((unsigned short)(u & 0xffff));
                o1 = bf2f((unsigned short)(u >> 16));
            } else {
                float2 u = *(const float2*)((const float*)origin + base);
                o0 = u.x; o1 = u.y;
            }
            float oo = o0 * o0 + o1 * o1;
            float ov = o0 * v0 + o1 * v1;
            for (int off = 32; off; off >>= 1) {
                oo += __shfl_xor(oo, off, 64);
                ov += __shfl_xor(ov, off, 64);
            }
            float cosn = ov / (sqrtf(fmaxf(oo, 1e-12f)) * sqrtf(fmaxf(vv, 1e-12f)));
            float nl = 0.5f * (1.f - cosn);
            accs += log1pf(expf(nl));
        }
        __syncthreads();
        if (lane == 0) red[wv] = accs;
        __syncthreads();
        if (t == 0) neg_sum[b] = red[0] + red[1] + red[2] + red[3];
    }
}

// ---------------- K3: aux[b] = sum_b'(pos_loss) + neg_sum[b] (f32) ----------------
__global__ __launch_bounds__(1024) void final_kernel(
    const float* __restrict__ pos_loss,
    const float* __restrict__ neg_sum,
    float* __restrict__ out)
{
    __shared__ float red[16];
    int t = threadIdx.x;
    float v = pos_loss[t];
    for (int off = 32; off; off >>= 1) v += __shfl_xor(v, off, 64);
    if ((t & 63) == 0) red[t >> 6] = v;
    __syncthreads();
    if (t == 0) {
        float s = 0.f;
#pragma unroll
        for (int i = 0; i < 16; ++i) s += red[i];
        red[0] = s;
    }
    __syncthreads();
    out[(size_t)B_ * (D_ + 1) + t] = red[0] + neg_sum[t];
}

extern "C" void kernel_launch(void* const* d_in, const int* in_sizes, int n_in,
                              void* d_out, int out_size, void* d_ws, size_t ws_size,
                              hipStream_t stream) {
    const void* Xs     = d_in[0]; // X_series [B,S,D]
    const void* pos    = d_in[1]; // pos_series [S,D]
    const void* Xitem  = d_in[2]; // X_item [B,D]
    const void* mask   = d_in[3]; // valid_mask [B,S]
    const void* origin = d_in[4]; // origin [B,N,D]
    const void* Wp     = d_in[5]; // [D,H]
    const void* We     = d_in[6]; // [D,H]
    const void* zv     = d_in[7]; // [H]

    int*   flags    = (int*)d_ws;                   // 32 ints (128 B)
    unsigned short* WeT = (unsigned short*)((char*)d_ws + 128);  // 16384 bf16 (32 KB), 16B-aligned
    float* ws       = (float*)((char*)d_ws + 128 + 32768);
    float* pb       = ws;                           // 25600 f32
    float* scores   = pb + 25600;                   // 204800 f32
    float* pos_loss = scores + 204800;              // 1024 f32
    float* neg_sum  = pos_loss + B_;                // 1024 f32
    float* out = (float*)d_out;                     // f32 output

    detect_kernel<<<8, 64, 0, stream>>>(Xs, pos, Xitem, mask, origin, Wp, We, zv, flags);
    prep_kernel<<<1, 1024, 0, stream>>>(We, flags, WeT);
    pb_kernel<<<S_, 128, 0, stream>>>(pos, Wp, flags, pb);
    scores_kernel<<<(B_ * S_) / 128, 256, 0, stream>>>(Xs, WeT, zv, pb, flags, scores);
    perB_kernel<<<B_, 256, 0, stream>>>(Xs, Xitem, mask, origin, scores, flags, pos_loss, neg_sum, out);
    final_kernel<<<1, 1024, 0, stream>>>(pos_loss, neg_sum, out);
}

// Round 5
// 273.085 us; speedup vs baseline: 1.1054x; 1.0508x over previous
//
#include <hip/hip_runtime.h>
#include <hip/hip_bf16.h>
#include <math.h>

#define B_ 1024
#define S_ 200
#define D_ 128
#define H_ 128
#define N_ 64
#define XP 136          // Xsh row pitch (bf16): 272 B -> 2-way LDS aliasing (free)

typedef __attribute__((ext_vector_type(8))) short short8;
typedef __attribute__((ext_vector_type(8))) __bf16 bf16x8;
typedef __attribute__((ext_vector_type(4))) float floatx4;

static __device__ __forceinline__ float bf2f(unsigned short u) {
    union { unsigned int i; float f; } v; v.i = ((unsigned int)u) << 16; return v.f;
}
static __device__ __forceinline__ unsigned short f2bf(float f) {
    union { float f; unsigned int u; } v; v.f = f;
    unsigned int u = v.u;
    return (unsigned short)((u + 0x7FFFu + ((u >> 16) & 1u)) >> 16);   // RNE
}
static __device__ __forceinline__ float ld1(const void* p, int isbf, size_t i) {
    return isbf ? bf2f(((const unsigned short*)p)[i]) : ((const float*)p)[i];
}
static __device__ __forceinline__ float fast_tanh(float x) {
    float t = __expf(2.0f * x);
    return 1.0f - 2.0f * __builtin_amdgcn_rcpf(t + 1.0f);   // err ~2e-5
}

// ---------------- K-1: dtype detection ----------------
__global__ __launch_bounds__(64) void detect_kernel(
    const void* a0, const void* a1, const void* a2, const void* a3,
    const void* a4, const void* a5, const void* a6, const void* a7,
    int* flags)
{
    int bid = blockIdx.x, t = threadIdx.x;
    if (bid == 3) {
        const unsigned char* mb = (const unsigned char*)a3;
        int f = 0;
        for (int i = t; i < 4096; i += 64)
            if ((i & 3) && mb[i]) f = 1;
        for (int off = 32; off; off >>= 1) f |= __shfl_xor(f, off, 64);
        if (t == 0) flags[3] = f;          // 1 => uint8 mask, 0 => int32 mask
        return;
    }
    const void* ptrs[8] = {a0, a1, a2, a3, a4, a5, a6, a7};
    const int counts[8] = {B_*S_*D_, S_*D_, B_*D_, 0, B_*N_*D_, D_*H_, D_*H_, H_};
    const unsigned int* w = (const unsigned int*)ptrs[bid];
    int words = counts[bid] / 2; if (words > 1024) words = 1024;
    int pass = 0, tot = 0;
    for (int i = t; i < words; i += 64) {
        unsigned int e = (w[i] >> 7) & 0xFF;
        tot++;
        if (e == 0 || (e >= 96 && e <= 140)) pass++;
    }
    for (int off = 32; off; off >>= 1) {
        pass += __shfl_xor(pass, off, 64);
        tot  += __shfl_xor(tot,  off, 64);
    }
    if (t == 0) flags[bid] = (pass * 4 >= tot * 3) ? 1 : 0;
}

// ---------------- prep: block 0 -> WeTf (fragment-swizzled); blocks 1..200 -> pb rows ----
// WeTf layout: frag = nt*4+kks (32 frags); within frag, lane-contiguous 8 bf16:
//   WeTf[(frag*64 + lane)*8 + j] = We[d = kks*32 + (lane>>4)*8 + j][h = nt*16 + (lane&15)]
__global__ __launch_bounds__(128) void prep_kernel(
    const void* __restrict__ We, const void* __restrict__ pos,
    const void* __restrict__ Wp, const int* __restrict__ flags,
    unsigned short* __restrict__ WeTf, float* __restrict__ pb)
{
    int blk = blockIdx.x, t = threadIdx.x;
    __shared__ unsigned short T[128][136];
    __shared__ float prow[D_];
    if (blk == 0) {
        int fWe = flags[6];
        for (int c = t; c < 2048; c += 128) {
            int d = c >> 4, h8 = (c & 15) * 8;
            short8 v;
            if (fWe) {
                v = *(const short8*)((const unsigned short*)We + d * H_ + h8);
            } else {
                const float* p = (const float*)We + d * H_ + h8;
                float4 a = ((const float4*)p)[0], b = ((const float4*)p)[1];
                v[0] = (short)f2bf(a.x); v[1] = (short)f2bf(a.y);
                v[2] = (short)f2bf(a.z); v[3] = (short)f2bf(a.w);
                v[4] = (short)f2bf(b.x); v[5] = (short)f2bf(b.y);
                v[6] = (short)f2bf(b.z); v[7] = (short)f2bf(b.w);
            }
            *(short8*)(&T[d][h8]) = v;
        }
        __syncthreads();
        for (int i = t; i < 2048; i += 128) {
            int frag = i >> 6, ln = i & 63;
            int nt = frag >> 2, kks = frag & 3;
            int h = nt * 16 + (ln & 15);
            int dbase = kks * 32 + (ln >> 4) * 8;
            short8 v;
#pragma unroll
            for (int j = 0; j < 8; ++j) v[j] = (short)T[dbase + j][h];
            *(short8*)(WeTf + (size_t)i * 8) = v;
        }
    } else {
        int s = blk - 1, h = t;
        prow[h] = ld1(pos, flags[1], (size_t)s * D_ + h);
        __syncthreads();
        float acc = 0.f;
        if (flags[5]) {
            const unsigned short* W = (const unsigned short*)Wp;
            for (int d = 0; d < D_; ++d) acc = fmaf(prow[d], bf2f(W[d * H_ + h]), acc);
        } else {
            const float* W = (const float*)Wp;
            for (int d = 0; d < D_; ++d) acc = fmaf(prow[d], W[d * H_ + h], acc);
        }
        pb[s * H_ + h] = acc;
    }
}

// ---------------- fused: one block per b — scores(MFMA) + softmax + everything ----------------
__global__ __launch_bounds__(256) void fused_kernel(
    const void* __restrict__ Xs, const void* __restrict__ Xitem,
    const void* __restrict__ maskv, const void* __restrict__ origin,
    const unsigned short* __restrict__ WeTf, const void* __restrict__ zv,
    const float* __restrict__ pb, const int* __restrict__ flags,
    float* __restrict__ pos_loss, float* __restrict__ neg_sum,
    float* __restrict__ out)
{
    int b = blockIdx.x, t = threadIdx.x;
    int wv = t >> 6, lane = t & 63;
    int quad = lane >> 4, mrow = lane & 15;
    int fXs = flags[0], fXi = flags[2], fMk = flags[3], fOr = flags[4], fz = flags[7];

    __shared__ unsigned short Xsh[208 * XP];   // 56576 B, bf16, padded rows
    __shared__ float attn[256];
    __shared__ float att_out[D_];
    __shared__ float lastv[D_];
    __shared__ float outv[D_];
    __shared__ float partial[8][D_];
    __shared__ float red[16];
    __shared__ int redi[4];
    __shared__ float sc1s, sc2s, sc3s;

    // --- length via ballot (runs before staging; mask is a contiguous prefix) ---
    int nz = 0;
    if (t < S_)
        nz = fMk ? (((const unsigned char*)maskv)[(size_t)b * S_ + t] != 0)
                 : (((const int*)maskv)[(size_t)b * S_ + t] != 0);
    unsigned long long bal = __ballot(nz);
    if (lane == 0) redi[wv] = __popcll(bal);

    // --- stage X[b] -> Xsh (bf16, pitch XP) ---
    if (fXs) {
        const unsigned short* Xb = (const unsigned short*)Xs + (size_t)b * S_ * D_;
        for (int idx = t; idx < 3200; idx += 256) {      // short8 chunks
            int s = idx >> 4, d8 = (idx & 15) * 8;
            short8 v = *(const short8*)(Xb + s * D_ + d8);
            *(short8*)(Xsh + s * XP + d8) = v;
        }
    } else {
        const float* Xb = (const float*)Xs + (size_t)b * S_ * D_;
        for (int idx = t; idx < 6400; idx += 256) {      // float4 chunks, lane-coalesced
            int s = idx >> 5, d4 = (idx & 31) * 4;
            float4 v = *(const float4*)(Xb + s * D_ + d4);
            uint2 u;
            u.x = (unsigned int)f2bf(v.x) | ((unsigned int)f2bf(v.y) << 16);
            u.y = (unsigned int)f2bf(v.z) | ((unsigned int)f2bf(v.w) << 16);
            *(uint2*)(Xsh + s * XP + d4) = u;
        }
    }
    // zero-pad rows 200..207 (only cols <128 are read)
    for (int i = t; i < 1024; i += 256) {
        int r = 200 + (i >> 7), c = i & 127;
        Xsh[r * XP + c] = 0;
    }

    float zl[8];
#pragma unroll
    for (int nt = 0; nt < 8; ++nt) zl[nt] = ld1(zv, fz, nt * 16 + mrow);

    __syncthreads();
    int length = redi[0] + redi[1] + redi[2] + redi[3];   // >= 1
    int last = length - 1;

    // --- MFMA scores: 13 m-tiles over 4 waves; A from LDS, B from WeTf (coalesced) ---
    for (int tile = wv; tile < 13; tile += 4) {
        int m0 = tile * 16;
        floatx4 acc[8];
#pragma unroll
        for (int nt = 0; nt < 8; ++nt) {
            acc[nt][0] = 0.f; acc[nt][1] = 0.f; acc[nt][2] = 0.f; acc[nt][3] = 0.f;
        }
        const unsigned short* arow = Xsh + (m0 + mrow) * XP;
#pragma unroll
        for (int kks = 0; kks < 4; ++kks) {
            short8 av = *(const short8*)(arow + kks * 32 + quad * 8);
            bf16x8 af = __builtin_bit_cast(bf16x8, av);
#pragma unroll
            for (int nt = 0; nt < 8; ++nt) {
                short8 bv = *(const short8*)(WeTf + (size_t)(((nt << 2) + kks) * 64 + lane) * 8);
                bf16x8 bf = __builtin_bit_cast(bf16x8, bv);
                acc[nt] = __builtin_amdgcn_mfma_f32_16x16x32_bf16(af, bf, acc[nt], 0, 0, 0);
            }
        }
        // epilogue: C layout col=mrow, row=quad*4+reg
#pragma unroll
        for (int reg = 0; reg < 4; ++reg) {
            int grow = m0 + quad * 4 + reg;              // = s index
            float rs = 0.f;
            if (grow < S_) {
                const float* pbrow = pb + (size_t)grow * H_;
#pragma unroll
                for (int nt = 0; nt < 8; ++nt)
                    rs = fmaf(fast_tanh(acc[nt][reg] + pbrow[nt * 16 + mrow]), zl[nt], rs);
            }
#pragma unroll
            for (int off = 1; off < 16; off <<= 1)
                rs += __shfl_xor(rs, off, 64);
            if (mrow == 0 && grow < S_) attn[grow] = rs;  // raw score
        }
    }
    __syncthreads();

    // --- softmax over valid prefix (in place in attn) ---
    float sc = (t < length) ? attn[t] : -INFINITY;
    float m = sc;
    for (int off = 32; off; off >>= 1) m = fmaxf(m, __shfl_xor(m, off, 64));
    if (lane == 0) red[wv] = m;
    __syncthreads();
    if (t == 0) sc1s = fmaxf(fmaxf(red[0], red[1]), fmaxf(red[2], red[3]));
    __syncthreads();
    float e = (t < length) ? expf(sc - sc1s) : 0.f;
    float r = e;
    for (int off = 32; off; off >>= 1) r += __shfl_xor(r, off, 64);
    __syncthreads();
    if (lane == 0) red[wv] = r;
    __syncthreads();
    if (t == 0) sc2s = red[0] + red[1] + red[2] + red[3];
    __syncthreads();
    attn[t] = e / sc2s;        // 0 beyond length (incl. 200..255)
    __syncthreads();

    // --- attention_output[d] = sum_s attn[s] * Xsh[s][d] (LDS only) ---
    {
        int part = t >> 5;             // s offset 0..7
        int d4 = (t & 31) * 4;
        float a0 = 0, a1 = 0, a2 = 0, a3 = 0;
#pragma unroll 5
        for (int s = part; s < S_; s += 8) {
            float ww = attn[s];
            uint2 u = *(const uint2*)(Xsh + s * XP + d4);
            a0 = fmaf(ww, bf2f((unsigned short)(u.x & 0xffff)), a0);
            a1 = fmaf(ww, bf2f((unsigned short)(u.x >> 16)), a1);
            a2 = fmaf(ww, bf2f((unsigned short)(u.y & 0xffff)), a2);
            a3 = fmaf(ww, bf2f((unsigned short)(u.y >> 16)), a3);
        }
        partial[part][d4] = a0; partial[part][d4 + 1] = a1;
        partial[part][d4 + 2] = a2; partial[part][d4 + 3] = a3;
    }
    __syncthreads();
    if (t < D_) {
        float v = 0.f;
#pragma unroll
        for (int p = 0; p < 8; ++p) v += partial[p][t];
        att_out[t] = v;
        float lv = attn[last] * bf2f(Xsh[last * XP + t]);
        lastv[t] = lv;
        outv[t] = v - lv;       // out_vec = attention_output - last_vec
    }
    __syncthreads();

    // --- inner = dot(att_out, X_item[b]); write concated row (f32) ---
    {
        float pi = (t < D_) ? att_out[t] * ld1(Xitem, fXi, (size_t)b * D_ + t) : 0.f;
        for (int off = 32; off; off >>= 1) pi += __shfl_xor(pi, off, 64);
        if (lane == 0) red[wv] = pi;
        __syncthreads();
        if (t < D_) out[(size_t)b * (D_ + 1) + t] = att_out[t];
        if (t == 0)
            out[(size_t)b * (D_ + 1) + D_] = red[0] + red[1] + red[2] + red[3];
        __syncthreads();
    }

    // --- pos loss: cos(last_vec, out_vec) ---
    {
        float l_ = (t < D_) ? lastv[t] : 0.f;
        float o_ = (t < D_) ? outv[t] : 0.f;
        float r0 = l_ * l_, r1 = l_ * o_, r2 = o_ * o_;
        for (int off = 32; off; off >>= 1) {
            r0 += __shfl_xor(r0, off, 64);
            r1 += __shfl_xor(r1, off, 64);
            r2 += __shfl_xor(r2, off, 64);
        }
        if (lane == 0) { red[wv] = r0; red[4 + wv] = r1; red[8 + wv] = r2; }
        __syncthreads();
        if (t == 0) {
            float ll = red[0] + red[1] + red[2] + red[3];
            float lo = red[4] + red[5] + red[6] + red[7];
            float oo = red[8] + red[9] + red[10] + red[11];
            float cosv = lo / (sqrtf(fmaxf(ll, 1e-12f)) * sqrtf(fmaxf(oo, 1e-12f)));
            float pl = 0.5f * (1.f - cosv);
            pos_loss[b] = log1pf(expf(-pl));
            sc3s = oo;
        }
        __syncthreads();
    }

    // --- neg losses: 64 origin vectors, 16 per wave ---
    {
        int d = lane * 2;
        float v0 = outv[d], v1 = outv[d + 1];
        float vv = sc3s;
        float accs = 0.f;
        for (int n = wv; n < N_; n += 4) {
            size_t base = ((size_t)b * N_ + n) * D_ + d;
            float o0, o1;
            if (fOr) {
                unsigned int u = *(const unsigned int*)((const unsigned short*)origin + base);
                o0 = bf2f((unsigned short)(u & 0xffff));
                o1 = bf2f((unsigned short)(u >> 16));
            } else {
                float2 u = *(const float2*)((const float*)origin + base);
                o0 = u.x; o1 = u.y;
            }
            float oo = o0 * o0 + o1 * o1;
            float ov = o0 * v0 + o1 * v1;
            for (int off = 32; off; off >>= 1) {
                oo += __shfl_xor(oo, off, 64);
                ov += __shfl_xor(ov, off, 64);
            }
            float cosn = ov / (sqrtf(fmaxf(oo, 1e-12f)) * sqrtf(fmaxf(vv, 1e-12f)));
            float nl = 0.5f * (1.f - cosn);
            accs += log1pf(expf(nl));
        }
        __syncthreads();
        if (lane == 0) red[wv] = accs;
        __syncthreads();
        if (t == 0) neg_sum[b] = red[0] + red[1] + red[2] + red[3];
    }
}

// ---------------- K3: aux[b] = sum_b'(pos_loss) + neg_sum[b] (f32) ----------------
__global__ __launch_bounds__(1024) void final_kernel(
    const float* __restrict__ pos_loss,
    const float* __restrict__ neg_sum,
    float* __restrict__ out)
{
    __shared__ float red[16];
    int t = threadIdx.x;
    float v = pos_loss[t];
    for (int off = 32; off; off >>= 1) v += __shfl_xor(v, off, 64);
    if ((t & 63) == 0) red[t >> 6] = v;
    __syncthreads();
    if (t == 0) {
        float s = 0.f;
#pragma unroll
        for (int i = 0; i < 16; ++i) s += red[i];
        red[0] = s;
    }
    __syncthreads();
    out[(size_t)B_ * (D_ + 1) + t] = red[0] + neg_sum[t];
}

extern "C" void kernel_launch(void* const* d_in, const int* in_sizes, int n_in,
                              void* d_out, int out_size, void* d_ws, size_t ws_size,
                              hipStream_t stream) {
    const void* Xs     = d_in[0]; // X_series [B,S,D]
    const void* pos    = d_in[1]; // pos_series [S,D]
    const void* Xitem  = d_in[2]; // X_item [B,D]
    const void* mask   = d_in[3]; // valid_mask [B,S]
    const void* origin = d_in[4]; // origin [B,N,D]
    const void* Wp     = d_in[5]; // [D,H]
    const void* We     = d_in[6]; // [D,H]
    const void* zv     = d_in[7]; // [H]

    int*   flags    = (int*)d_ws;                                  // 128 B
    unsigned short* WeTf = (unsigned short*)((char*)d_ws + 128);   // 32 KB swizzled
    float* pb       = (float*)((char*)d_ws + 128 + 32768);         // 25600 f32
    float* pos_loss = pb + 25600;                                  // 1024 f32
    float* neg_sum  = pos_loss + B_;                               // 1024 f32
    float* out = (float*)d_out;                                    // f32 output

    detect_kernel<<<8, 64, 0, stream>>>(Xs, pos, Xitem, mask, origin, Wp, We, zv, flags);
    prep_kernel<<<201, 128, 0, stream>>>(We, pos, Wp, flags, WeTf, pb);
    fused_kernel<<<B_, 256, 0, stream>>>(Xs, Xitem, mask, origin, WeTf, zv, pb, flags,
                                         pos_loss, neg_sum, out);
    final_kernel<<<1, 1024, 0, stream>>>(pos_loss, neg_sum, out);
}

// Round 6
// 268.088 us; speedup vs baseline: 1.1260x; 1.0186x over previous
//
#include <hip/hip_runtime.h>
#include <hip/hip_bf16.h>
#include <math.h>

#define B_ 1024
#define S_ 200
#define D_ 128
#define H_ 128
#define N_ 64

typedef __attribute__((ext_vector_type(8))) short short8;
typedef __attribute__((ext_vector_type(8))) __bf16 bf16x8;
typedef __attribute__((ext_vector_type(4))) float floatx4;

static __device__ __forceinline__ float bf2f(unsigned short u) {
    union { unsigned int i; float f; } v; v.i = ((unsigned int)u) << 16; return v.f;
}
static __device__ __forceinline__ unsigned short f2bf(float f) {
    union { float f; unsigned int u; } v; v.f = f;
    unsigned int u = v.u;
    return (unsigned short)((u + 0x7FFFu + ((u >> 16) & 1u)) >> 16);   // RNE
}
static __device__ __forceinline__ float ld1(const void* p, int isbf, size_t i) {
    return isbf ? bf2f(((const unsigned short*)p)[i]) : ((const float*)p)[i];
}
static __device__ __forceinline__ float fast_tanh(float x) {
    float t = __expf(2.0f * x);
    return 1.0f - 2.0f * __builtin_amdgcn_rcpf(t + 1.0f);   // err ~2e-5
}

// ---------------- K-1: dtype detection ----------------
__global__ __launch_bounds__(64) void detect_kernel(
    const void* a0, const void* a1, const void* a2, const void* a3,
    const void* a4, const void* a5, const void* a6, const void* a7,
    int* flags)
{
    int bid = blockIdx.x, t = threadIdx.x;
    if (bid == 3) {
        const unsigned char* mb = (const unsigned char*)a3;
        int f = 0;
        for (int i = t; i < 4096; i += 64)
            if ((i & 3) && mb[i]) f = 1;
        for (int off = 32; off; off >>= 1) f |= __shfl_xor(f, off, 64);
        if (t == 0) flags[3] = f;          // 1 => uint8 mask, 0 => int32 mask
        return;
    }
    const void* ptrs[8] = {a0, a1, a2, a3, a4, a5, a6, a7};
    const int counts[8] = {B_*S_*D_, S_*D_, B_*D_, 0, B_*N_*D_, D_*H_, D_*H_, H_};
    const unsigned int* w = (const unsigned int*)ptrs[bid];
    int words = counts[bid] / 2; if (words > 1024) words = 1024;
    int pass = 0, tot = 0;
    for (int i = t; i < words; i += 64) {
        unsigned int e = (w[i] >> 7) & 0xFF;
        tot++;
        if (e == 0 || (e >= 96 && e <= 140)) pass++;
    }
    for (int off = 32; off; off >>= 1) {
        pass += __shfl_xor(pass, off, 64);
        tot  += __shfl_xor(tot,  off, 64);
    }
    if (t == 0) flags[bid] = (pass * 4 >= tot * 3) ? 1 : 0;
}

// ---------------- prep: block 0 -> WeTf (fragment-swizzled); blocks 1..200 -> pb rows ----
// WeTf layout: frag = nt*4+kks; WeTf[(frag*64+lane)*8+j] = We[kks*32+(lane>>4)*8+j][nt*16+(lane&15)]
__global__ __launch_bounds__(128) void prep_kernel(
    const void* __restrict__ We, const void* __restrict__ pos,
    const void* __restrict__ Wp, const int* __restrict__ flags,
    unsigned short* __restrict__ WeTf, float* __restrict__ pb)
{
    int blk = blockIdx.x, t = threadIdx.x;
    __shared__ unsigned short T[128][136];
    __shared__ float prow[D_];
    if (blk == 0) {
        int fWe = flags[6];
        for (int c = t; c < 2048; c += 128) {
            int d = c >> 4, h8 = (c & 15) * 8;
            short8 v;
            if (fWe) {
                v = *(const short8*)((const unsigned short*)We + d * H_ + h8);
            } else {
                const float* p = (const float*)We + d * H_ + h8;
                float4 a = ((const float4*)p)[0], b = ((const float4*)p)[1];
                v[0] = (short)f2bf(a.x); v[1] = (short)f2bf(a.y);
                v[2] = (short)f2bf(a.z); v[3] = (short)f2bf(a.w);
                v[4] = (short)f2bf(b.x); v[5] = (short)f2bf(b.y);
                v[6] = (short)f2bf(b.z); v[7] = (short)f2bf(b.w);
            }
            *(short8*)(&T[d][h8]) = v;
        }
        __syncthreads();
        for (int i = t; i < 2048; i += 128) {
            int frag = i >> 6, ln = i & 63;
            int nt = frag >> 2, kks = frag & 3;
            int h = nt * 16 + (ln & 15);
            int dbase = kks * 32 + (ln >> 4) * 8;
            short8 v;
#pragma unroll
            for (int j = 0; j < 8; ++j) v[j] = (short)T[dbase + j][h];
            *(short8*)(WeTf + (size_t)i * 8) = v;
        }
    } else {
        int s = blk - 1, h = t;
        prow[h] = ld1(pos, flags[1], (size_t)s * D_ + h);
        __syncthreads();
        float acc = 0.f;
        if (flags[5]) {
            const unsigned short* W = (const unsigned short*)Wp;
            for (int d = 0; d < D_; ++d) acc = fmaf(prow[d], bf2f(W[d * H_ + h]), acc);
        } else {
            const float* W = (const float*)Wp;
            for (int d = 0; d < D_; ++d) acc = fmaf(prow[d], W[d * H_ + h], acc);
        }
        pb[s * H_ + h] = acc;
    }
}

// ---------------- K1: scores GEMM — A from global (stream X), B frags from LDS ----------------
// Block = 256 thr (4 waves), M = 128 rows/block (2 m-tiles/wave), grid = 1600.
__global__ __launch_bounds__(256) void scores_kernel(
    const void* __restrict__ Xs, const unsigned short* __restrict__ WeTf,
    const void* __restrict__ zv, const float* __restrict__ pb,
    const int* __restrict__ flags, float* __restrict__ scores)
{
    __shared__ unsigned short Bsh[16384];   // 32 KB, frag-contiguous (same layout as WeTf)
    int t = threadIdx.x;
    int lane = t & 63, w = t >> 6;
    int quad = lane >> 4, mrow = lane & 15;
    int fXs = flags[0], fz = flags[7];
    int row0 = blockIdx.x * 128 + w * 32;

    // one-time B stage: 8 coalesced 16B copies per thread
    for (int i = t; i < 2048; i += 256)
        *(short8*)(Bsh + i * 8) = *(const short8*)(WeTf + (size_t)i * 8);

    float zl[8];
#pragma unroll
    for (int nt = 0; nt < 8; ++nt) zl[nt] = ld1(zv, fz, nt * 16 + mrow);

    floatx4 acc[2][8];
#pragma unroll
    for (int mt = 0; mt < 2; ++mt)
#pragma unroll
        for (int nt = 0; nt < 8; ++nt) {
            acc[mt][nt][0] = 0.f; acc[mt][nt][1] = 0.f;
            acc[mt][nt][2] = 0.f; acc[mt][nt][3] = 0.f;
        }
    __syncthreads();

#pragma unroll
    for (int kks = 0; kks < 4; ++kks) {
        bf16x8 af[2];
#pragma unroll
        for (int mt = 0; mt < 2; ++mt) {
            size_t roff = (size_t)(row0 + mt * 16 + mrow) * D_ + kks * 32 + quad * 8;
            if (fXs) {
                short8 v = *(const short8*)((const unsigned short*)Xs + roff);
                af[mt] = __builtin_bit_cast(bf16x8, v);
            } else {
                const float* p = (const float*)Xs + roff;
                float4 a = ((const float4*)p)[0], b = ((const float4*)p)[1];
                short8 v;
                v[0] = (short)f2bf(a.x); v[1] = (short)f2bf(a.y);
                v[2] = (short)f2bf(a.z); v[3] = (short)f2bf(a.w);
                v[4] = (short)f2bf(b.x); v[5] = (short)f2bf(b.y);
                v[6] = (short)f2bf(b.z); v[7] = (short)f2bf(b.w);
                af[mt] = __builtin_bit_cast(bf16x8, v);
            }
        }
#pragma unroll
        for (int nt = 0; nt < 8; ++nt) {
            short8 bv = *(const short8*)(Bsh + (((nt << 2) + kks) * 64 + lane) * 8);
            bf16x8 bf = __builtin_bit_cast(bf16x8, bv);
            acc[0][nt] = __builtin_amdgcn_mfma_f32_16x16x32_bf16(af[0], bf, acc[0][nt], 0, 0, 0);
            acc[1][nt] = __builtin_amdgcn_mfma_f32_16x16x32_bf16(af[1], bf, acc[1][nt], 0, 0, 0);
        }
    }

    // epilogue: C layout col=mrow, row=quad*4+reg
#pragma unroll
    for (int mt = 0; mt < 2; ++mt) {
#pragma unroll
        for (int reg = 0; reg < 4; ++reg) {
            int grow = row0 + mt * 16 + quad * 4 + reg;
            int s = grow % S_;
            const float* pbrow = pb + (size_t)s * H_;
            float rs = 0.f;
#pragma unroll
            for (int nt = 0; nt < 8; ++nt)
                rs = fmaf(fast_tanh(acc[mt][nt][reg] + pbrow[nt * 16 + mrow]), zl[nt], rs);
#pragma unroll
            for (int off = 1; off < 16; off <<= 1)
                rs += __shfl_xor(rs, off, 64);
            if (mrow == 0) scores[grow] = rs;
        }
    }
}

// ---------------- K2: per-b softmax, weighted sum, inner, pos/neg losses ----------------
__global__ __launch_bounds__(256) void attnout_kernel(
    const void* __restrict__ Xs, const void* __restrict__ Xitem,
    const void* __restrict__ maskv, const void* __restrict__ origin,
    const float* __restrict__ scores, const int* __restrict__ flags,
    float* __restrict__ pos_loss, float* __restrict__ neg_sum,
    float* __restrict__ out)
{
    int b = blockIdx.x, t = threadIdx.x;
    int wv = t >> 6, lane = t & 63;
    int fXs = flags[0], fXi = flags[2], fMk = flags[3], fOr = flags[4];
    __shared__ float attn[256];
    __shared__ float att_out[D_];
    __shared__ float lastv[D_];
    __shared__ float outv[D_];
    __shared__ float partial[8][D_];
    __shared__ float p_oo[4][64];
    __shared__ float p_ov[4][64];
    __shared__ float red[16];
    __shared__ int redi[4];
    __shared__ float sc1s, sc2s, vvs;

    // --- preload this thread's origin slice into registers (latency hidden) ---
    int nn = t >> 2, part = t & 3;       // thread -> (n, quarter-of-D)
    float o_f[32];
    if (fOr) {
        const unsigned short* p = (const unsigned short*)origin + ((size_t)b * N_ + nn) * D_ + part * 32;
#pragma unroll
        for (int j = 0; j < 4; ++j) {
            uint4 u = *(const uint4*)(p + j * 8);
            o_f[j*8+0] = bf2f((unsigned short)(u.x & 0xffff));
            o_f[j*8+1] = bf2f((unsigned short)(u.x >> 16));
            o_f[j*8+2] = bf2f((unsigned short)(u.y & 0xffff));
            o_f[j*8+3] = bf2f((unsigned short)(u.y >> 16));
            o_f[j*8+4] = bf2f((unsigned short)(u.z & 0xffff));
            o_f[j*8+5] = bf2f((unsigned short)(u.z >> 16));
            o_f[j*8+6] = bf2f((unsigned short)(u.w & 0xffff));
            o_f[j*8+7] = bf2f((unsigned short)(u.w >> 16));
        }
    } else {
        const float* p = (const float*)origin + ((size_t)b * N_ + nn) * D_ + part * 32;
#pragma unroll
        for (int j = 0; j < 8; ++j) {
            float4 v = *(const float4*)(p + j * 4);
            o_f[j*4+0] = v.x; o_f[j*4+1] = v.y; o_f[j*4+2] = v.z; o_f[j*4+3] = v.w;
        }
    }

    // --- length via ballot (mask is a contiguous prefix) ---
    int nz = 0;
    if (t < S_)
        nz = fMk ? (((const unsigned char*)maskv)[(size_t)b * S_ + t] != 0)
                 : (((const int*)maskv)[(size_t)b * S_ + t] != 0);
    unsigned long long bal = __ballot(nz);
    if (lane == 0) redi[wv] = __popcll(bal);
    __syncthreads();
    int length = redi[0] + redi[1] + redi[2] + redi[3];   // >= 1
    int last = length - 1;

    // --- softmax over valid prefix ---
    float sc = (t < length) ? scores[(size_t)b * S_ + t] : -INFINITY;
    float m = sc;
    for (int off = 32; off; off >>= 1) m = fmaxf(m, __shfl_xor(m, off, 64));
    if (lane == 0) red[wv] = m;
    __syncthreads();
    if (t == 0) sc1s = fmaxf(fmaxf(red[0], red[1]), fmaxf(red[2], red[3]));
    __syncthreads();
    float e = (t < length) ? expf(sc - sc1s) : 0.f;
    float r = e;
    for (int off = 32; off; off >>= 1) r += __shfl_xor(r, off, 64);
    __syncthreads();
    if (lane == 0) red[wv] = r;
    __syncthreads();
    if (t == 0) sc2s = red[0] + red[1] + red[2] + red[3];
    __syncthreads();
    attn[t] = e / sc2s;       // 0 beyond length (incl. 200..255)
    __syncthreads();

    // --- attention_output[d] = sum_s attn[s] * X[b,s,d]; fixed 25-trip loop ---
    {
        int sp = t >> 5;               // s offset 0..7
        int d4 = (t & 31) * 4;         // 4 contiguous d
        float a0 = 0, a1 = 0, a2 = 0, a3 = 0;
        if (fXs) {
#pragma unroll 5
            for (int s = sp; s < S_; s += 8) {
                float ww = attn[s];
                uint2 u = *(const uint2*)((const unsigned short*)Xs + ((size_t)b * S_ + s) * D_ + d4);
                a0 = fmaf(ww, bf2f((unsigned short)(u.x & 0xffff)), a0);
                a1 = fmaf(ww, bf2f((unsigned short)(u.x >> 16)), a1);
                a2 = fmaf(ww, bf2f((unsigned short)(u.y & 0xffff)), a2);
                a3 = fmaf(ww, bf2f((unsigned short)(u.y >> 16)), a3);
            }
        } else {
#pragma unroll 5
            for (int s = sp; s < S_; s += 8) {
                float ww = attn[s];
                float4 u = *(const float4*)((const float*)Xs + ((size_t)b * S_ + s) * D_ + d4);
                a0 = fmaf(ww, u.x, a0);
                a1 = fmaf(ww, u.y, a1);
                a2 = fmaf(ww, u.z, a2);
                a3 = fmaf(ww, u.w, a3);
            }
        }
        partial[sp][d4] = a0; partial[sp][d4 + 1] = a1;
        partial[sp][d4 + 2] = a2; partial[sp][d4 + 3] = a3;
    }
    __syncthreads();
    if (t < D_) {
        float v = 0.f;
#pragma unroll
        for (int p = 0; p < 8; ++p) v += partial[p][t];
        att_out[t] = v;
        float lv = attn[last] * ld1(Xs, fXs, ((size_t)b * S_ + last) * D_ + t);
        lastv[t] = lv;
        outv[t] = v - lv;       // out_vec = attention_output - last_vec
    }
    __syncthreads();

    // --- inner = dot(att_out, X_item[b]); write concated row (f32) ---
    {
        float pi = (t < D_) ? att_out[t] * ld1(Xitem, fXi, (size_t)b * D_ + t) : 0.f;
        for (int off = 32; off; off >>= 1) pi += __shfl_xor(pi, off, 64);
        if (lane == 0) red[wv] = pi;
        __syncthreads();
        if (t < D_) out[(size_t)b * (D_ + 1) + t] = att_out[t];
        if (t == 0)
            out[(size_t)b * (D_ + 1) + D_] = red[0] + red[1] + red[2] + red[3];
        __syncthreads();
    }

    // --- pos loss: cos(last_vec, out_vec) ---
    {
        float l_ = (t < D_) ? lastv[t] : 0.f;
        float o_ = (t < D_) ? outv[t] : 0.f;
        float r0 = l_ * l_, r1 = l_ * o_, r2 = o_ * o_;
        for (int off = 32; off; off >>= 1) {
            r0 += __shfl_xor(r0, off, 64);
            r1 += __shfl_xor(r1, off, 64);
            r2 += __shfl_xor(r2, off, 64);
        }
        if (lane == 0) { red[wv] = r0; red[4 + wv] = r1; red[8 + wv] = r2; }
        __syncthreads();
        if (t == 0) {
            float ll = red[0] + red[1] + red[2] + red[3];
            float lo = red[4] + red[5] + red[6] + red[7];
            float oo = red[8] + red[9] + red[10] + red[11];
            float cosv = lo / (sqrtf(fmaxf(ll, 1e-12f)) * sqrtf(fmaxf(oo, 1e-12f)));
            float pl = 0.5f * (1.f - cosv);
            pos_loss[b] = log1pf(expf(-pl));
            vvs = oo;
        }
        __syncthreads();
    }

    // --- neg losses: thread (nn,part) computes quarter-dot; LDS reduce ---
    {
        float o_oo = 0.f, o_ov = 0.f;
#pragma unroll
        for (int jj = 0; jj < 32; ++jj) {
            int j = (jj + part * 8) & 31;           // bank-rotated outv read
            float wv_ = outv[part * 32 + j];
            o_oo = fmaf(o_f[j], o_f[j], o_oo);
            o_ov = fmaf(o_f[j], wv_, o_ov);
        }
        p_oo[part][nn] = o_oo;
        p_ov[part][nn] = o_ov;
        __syncthreads();
        if (t < 64) {
            float oo = p_oo[0][t] + p_oo[1][t] + p_oo[2][t] + p_oo[3][t];
            float ov = p_ov[0][t] + p_ov[1][t] + p_ov[2][t] + p_ov[3][t];
            float cosn = ov / (sqrtf(fmaxf(oo, 1e-12f)) * sqrtf(fmaxf(vvs, 1e-12f)));
            float nl = 0.5f * (1.f - cosn);
            float nloss = log1pf(expf(nl));
            for (int off = 32; off; off >>= 1) nloss += __shfl_xor(nloss, off, 64);
            if (t == 0) neg_sum[b] = nloss;
        }
    }
}

// ---------------- K3: aux[b] = sum_b'(pos_loss) + neg_sum[b] (f32) ----------------
__global__ __launch_bounds__(1024) void final_kernel(
    const float* __restrict__ pos_loss,
    const float* __restrict__ neg_sum,
    float* __restrict__ out)
{
    __shared__ float red[16];
    int t = threadIdx.x;
    float v = pos_loss[t];
    for (int off = 32; off; off >>= 1) v += __shfl_xor(v, off, 64);
    if ((t & 63) == 0) red[t >> 6] = v;
    __syncthreads();
    if (t == 0) {
        float s = 0.f;
#pragma unroll
        for (int i = 0; i < 16; ++i) s += red[i];
        red[0] = s;
    }
    __syncthreads();
    out[(size_t)B_ * (D_ + 1) + t] = red[0] + neg_sum[t];
}

extern "C" void kernel_launch(void* const* d_in, const int* in_sizes, int n_in,
                              void* d_out, int out_size, void* d_ws, size_t ws_size,
                              hipStream_t stream) {
    const void* Xs     = d_in[0]; // X_series [B,S,D]
    const void* pos    = d_in[1]; // pos_series [S,D]
    const void* Xitem  = d_in[2]; // X_item [B,D]
    const void* mask   = d_in[3]; // valid_mask [B,S]
    const void* origin = d_in[4]; // origin [B,N,D]
    const void* Wp     = d_in[5]; // [D,H]
    const void* We     = d_in[6]; // [D,H]
    const void* zv     = d_in[7]; // [H]

    int*   flags    = (int*)d_ws;                                  // 128 B
    unsigned short* WeTf = (unsigned short*)((char*)d_ws + 128);   // 32 KB swizzled
    float* pb       = (float*)((char*)d_ws + 128 + 32768);         // 25600 f32
    float* scores   = pb + 25600;                                  // 204800 f32
    float* pos_loss = scores + 204800;                             // 1024 f32
    float* neg_sum  = pos_loss + B_;                               // 1024 f32
    float* out = (float*)d_out;                                    // f32 output

    detect_kernel<<<8, 64, 0, stream>>>(Xs, pos, Xitem, mask, origin, Wp, We, zv, flags);
    prep_kernel<<<201, 128, 0, stream>>>(We, pos, Wp, flags, WeTf, pb);
    scores_kernel<<<(B_ * S_) / 128, 256, 0, stream>>>(Xs, WeTf, zv, pb, flags, scores);
    attnout_kernel<<<B_, 256, 0, stream>>>(Xs, Xitem, mask, origin, scores, flags,
                                           pos_loss, neg_sum, out);
    final_kernel<<<1, 1024, 0, stream>>>(pos_loss, neg_sum, out);
}